// Round 4
// baseline (224.562 us; speedup 1.0000x reference)
//
#include <hip/hip_runtime.h>
#include <math.h>

#define VOX 262144  // 64^3

__device__ __forceinline__ int clampi(int v, int lo, int hi) {
    return v < lo ? lo : (v > hi ? hi : v);
}

__device__ __forceinline__ float fast_tanh(float x) {
    float e = __expf(2.f * x);
    return 1.f - 2.f / (e + 1.f);
}

// ---- merged setup: feat transpose (blocks 0..8191), stats zero (8192),
//      weight transpose (8193..8208) ----
__global__ void k_setup(const float* __restrict__ f, float* __restrict__ ft,
                        float* __restrict__ stats, const float* __restrict__ w,
                        float* __restrict__ wT) {
    int bid = blockIdx.x;
    if (bid < 8192) {
        int idx = bid * 256 + threadIdx.x;  // (ci,z,y,x), coalesced reads
        int x = idx & 63, y = (idx >> 6) & 63, z = (idx >> 12) & 63, ci = idx >> 18;
        ft[(((z * 64 + y) * 64 + x) << 3) + ci] = f[idx];
    } else if (bid == 8192) {
        if (threadIdx.x < 64) stats[threadIdx.x] = 0.f;
    } else {
        int i = (bid - 8193) * 256 + threadIdx.x;  // over 18*8*27 = 3888
        if (i < 3888) {
            int c = i / 216, r = i % 216;
            int ci = r / 27, k = r % 27;
            wT[(k * 8 + ci) * 18 + c] = w[i];  // wT[k][ci][18]
        }
    }
}

// ---- offset conv (3x3x3, 8->18ch) + BN stats; CHANNEL-split across 2 groups ----
// 2048 blocks x 256: threads 0-127 compute out-ch 0..8, threads 128-255 ch 9..17
// for the same 128 voxels. Both groups load identical f values (L1 broadcast);
// x-neighbors via __shfl; weights scalar via readfirstlane'd group index.
__global__ __launch_bounds__(256, 8) void k_conv_off(
        const float* __restrict__ f, const float* __restrict__ wT,
        const float* __restrict__ b, float* __restrict__ offs,
        float* __restrict__ stats) {
    __shared__ float ls[36];
    if (threadIdx.x < 36) ls[threadIdx.x] = 0.f;

    int lv = threadIdx.x & 127;
    int g = __builtin_amdgcn_readfirstlane(threadIdx.x >> 7);  // 0/1, scalar
    int lane = threadIdx.x & 63;
    int vox = blockIdx.x * 128 + lv;
    int h = vox & 63, wy = (vox >> 6) & 63, d = vox >> 12;  // h == lane

    float mh0 = h > 0 ? 1.f : 0.f;
    float mh2 = h < 63 ? 1.f : 0.f;
    int sl0 = lane > 0 ? lane - 1 : 0;
    int sl2 = lane < 63 ? lane + 1 : 63;

    const float* wb = wT + 9 * g;  // scalar base -> s_load weights
    const float* bb = b + 9 * g;

    float acc[9];
#pragma unroll
    for (int c = 0; c < 9; c++) acc[c] = bb[c];

#pragma unroll
    for (int p = 0; p < 9; p++) {
        int kd = p / 3, kw = p % 3;
        int dd = d + kd - 1;
        int ww = wy + kw - 1;
        bool ok = ((unsigned)dd < 64u) & ((unsigned)ww < 64u);  // wave-uniform
        if (ok) {
            const float* fp = f + (dd * 64 + ww) * 64 + h;
#pragma unroll
            for (int ci = 0; ci < 8; ci++) {
                float v1 = fp[ci * VOX];
                float v0 = __shfl(v1, sl0) * mh0;
                float v2 = __shfl(v1, sl2) * mh2;
                // wT[((p*3+kh)*8+ci)*18 + 9g + c]
                const float* wp = wb + ((p * 3) * 8 + ci) * 18;
#pragma unroll
                for (int c = 0; c < 9; c++) {
                    float a = acc[c];
                    a = fmaf(v0, wp[c], a);
                    a = fmaf(v1, wp[8 * 18 + c], a);
                    a = fmaf(v2, wp[16 * 18 + c], a);
                    acc[c] = a;
                }
            }
        }
    }

#pragma unroll
    for (int c = 0; c < 9; c++) offs[(9 * g + c) * VOX + vox] = acc[c];

    __syncthreads();  // ls zeroed before atomics
#pragma unroll
    for (int c = 0; c < 9; c++) {
        float s = acc[c], q = acc[c] * acc[c];
#pragma unroll
        for (int o = 32; o > 0; o >>= 1) {
            s += __shfl_xor(s, o);
            q += __shfl_xor(q, o);
        }
        if (lane == 0) {
            atomicAdd(&ls[9 * g + c], s);
            atomicAdd(&ls[18 + 9 * g + c], q);
        }
    }
    __syncthreads();
    if (threadIdx.x < 36) atomicAdd(&stats[threadIdx.x], ls[threadIdx.x]);
}

// ---- main: BN+tanh+cumsum + bilinear(z,y) gather + (1,1,9) conv + GN stats.
//      One thread/voxel; corner gathers software-pipelined one tap ahead. ----
__global__ __launch_bounds__(256, 4) void k_main(
        const float* __restrict__ ft, const float* __restrict__ offs,
        const float* __restrict__ stats, const float* __restrict__ bn_g,
        const float* __restrict__ bn_b, const float* __restrict__ dw,
        const float* __restrict__ db, float* __restrict__ out,
        float* __restrict__ gstats) {
    __shared__ float ls[8];
    if (threadIdx.x < 8) ls[threadIdx.x] = 0.f;

    int idx = blockIdx.x * 256 + threadIdx.x;
    int h = idx & 63, wy = (idx >> 6) & 63, d = idx >> 12;
    int lane = threadIdx.x & 63;
    const float inv = 1.f / (float)VOX;

    float zo[9], yo[9];
#pragma unroll
    for (int c = 0; c < 18; c++) {
        float m = stats[c] * inv;
        float var = stats[18 + c] * inv - m * m;
        float rs = rsqrtf(var + 1e-5f);
        float t = fast_tanh(bn_g[c] * ((offs[c * VOX + idx] - m) * rs) + bn_b[c]);
        if (c < 9) zo[c] = t; else yo[c - 9] = t;
    }

    float za[9], ya[9];
    za[4] = zo[4]; ya[4] = yo[4];
#pragma unroll
    for (int k = 5; k < 9; k++) { za[k] = za[k - 1] + zo[k]; ya[k] = ya[k - 1] + yo[k]; }
#pragma unroll
    for (int k = 3; k >= 0; k--) { za[k] = za[k + 1] + zo[k]; ya[k] = ya[k + 1] + yo[k]; }

    float acc[16];
#pragma unroll
    for (int co = 0; co < 16; co++) acc[co] = db[co];

    // --- tap address/weight computation; uniform control flow (weight=0 when
    //     x out of range; clamped addresses are always valid) ---
#define TAP(K, W00, W01, W10, W11, P00, P01, P10, P11) {                     \
        int xi = h + (K) - 4;                                                \
        bool in = (xi >= 0) && (xi <= 62);                                   \
        int xc = in ? xi : 0;                                                \
        float z = (float)d + za[K];                                          \
        float y = (float)wy + ya[K];                                         \
        int iz = (int)floorf(z), iy = (int)floorf(y);                        \
        int z0 = clampi(iz, 0, 63), z1 = clampi(iz + 1, 0, 63);              \
        int y0 = clampi(iy, 0, 63), y1 = clampi(iy + 1, 0, 63);              \
        float wz0 = (float)z1 - z, wz1 = z - (float)z0;                      \
        float wu0 = (float)y1 - y, wu1 = y - (float)y0;                      \
        float s = in ? 1.f : 0.f;                                            \
        W00 = s * wz0 * wu0; W01 = s * wz0 * wu1;                            \
        W10 = s * wz1 * wu0; W11 = s * wz1 * wu1;                            \
        P00 = (const float4*)(ft + (((z0 * 64 + y0) * 64 + xc) << 3));       \
        P01 = (const float4*)(ft + (((z0 * 64 + y1) * 64 + xc) << 3));       \
        P10 = (const float4*)(ft + (((z1 * 64 + y0) * 64 + xc) << 3));       \
        P11 = (const float4*)(ft + (((z1 * 64 + y1) * 64 + xc) << 3));       \
    }

    float w00, w01, w10, w11;
    float4 cc0, cc1, cc2, cc3, cc4, cc5, cc6, cc7;
    {
        const float4 *p00, *p01, *p10, *p11;
        TAP(0, w00, w01, w10, w11, p00, p01, p10, p11);
        cc0 = p00[0]; cc1 = p00[1]; cc2 = p01[0]; cc3 = p01[1];
        cc4 = p10[0]; cc5 = p10[1]; cc6 = p11[0]; cc7 = p11[1];
    }

#pragma unroll
    for (int k = 0; k < 9; k++) {
        // stash current tap's data/weights
        float u00 = w00, u01 = w01, u10 = w10, u11 = w11;
        float4 e0 = cc0, e1 = cc1, e2 = cc2, e3 = cc3;
        float4 e4 = cc4, e5 = cc5, e6 = cc6, e7 = cc7;
        if (k < 8) {  // issue next tap's 8 gathers before this tap's FMAs
            const float4 *p00, *p01, *p10, *p11;
            TAP(k + 1, w00, w01, w10, w11, p00, p01, p10, p11);
            cc0 = p00[0]; cc1 = p00[1]; cc2 = p01[0]; cc3 = p01[1];
            cc4 = p10[0]; cc5 = p10[1]; cc6 = p11[0]; cc7 = p11[1];
        }

        float v[8];
        v[0] = u00 * e0.x + u01 * e2.x + u10 * e4.x + u11 * e6.x;
        v[1] = u00 * e0.y + u01 * e2.y + u10 * e4.y + u11 * e6.y;
        v[2] = u00 * e0.z + u01 * e2.z + u10 * e4.z + u11 * e6.z;
        v[3] = u00 * e0.w + u01 * e2.w + u10 * e4.w + u11 * e6.w;
        v[4] = u00 * e1.x + u01 * e3.x + u10 * e5.x + u11 * e7.x;
        v[5] = u00 * e1.y + u01 * e3.y + u10 * e5.y + u11 * e7.y;
        v[6] = u00 * e1.z + u01 * e3.z + u10 * e5.z + u11 * e7.z;
        v[7] = u00 * e1.w + u01 * e3.w + u10 * e5.w + u11 * e7.w;

#pragma unroll
        for (int ci = 0; ci < 8; ci++) {
#pragma unroll
            for (int co = 0; co < 16; co++)
                acc[co] = fmaf(v[ci], dw[(co * 8 + ci) * 9 + k], acc[co]);
        }
    }
#undef TAP

#pragma unroll
    for (int co = 0; co < 16; co++) out[co * VOX + idx] = acc[co];

    __syncthreads();  // ls zeroed before atomics
#pragma unroll
    for (int g = 0; g < 4; g++) {
        float s = acc[4 * g] + acc[4 * g + 1] + acc[4 * g + 2] + acc[4 * g + 3];
        float q = acc[4 * g] * acc[4 * g] + acc[4 * g + 1] * acc[4 * g + 1]
                + acc[4 * g + 2] * acc[4 * g + 2] + acc[4 * g + 3] * acc[4 * g + 3];
#pragma unroll
        for (int o = 32; o > 0; o >>= 1) {
            s += __shfl_xor(s, o);
            q += __shfl_xor(q, o);
        }
        if (lane == 0) {
            atomicAdd(&ls[g], s);
            atomicAdd(&ls[4 + g], q);
        }
    }
    __syncthreads();
    if (threadIdx.x < 8) atomicAdd(&gstats[threadIdx.x], ls[threadIdx.x]);
}

// ---- apply GroupNorm + ReLU in place on d_out ----
__global__ void k_gn(const float* __restrict__ gstats, const float* __restrict__ gn_g,
                     const float* __restrict__ gn_b, float* __restrict__ out) {
    int idx = blockIdx.x * 256 + threadIdx.x;  // 16*VOX elements
    int c = idx >> 18;
    int g = c >> 2;
    const float invn = 1.f / (4.f * (float)VOX);
    float m = gstats[g] * invn;
    float var = gstats[4 + g] * invn - m * m;
    float rs = rsqrtf(var + 1e-5f);
    float v = (out[idx] - m) * rs * gn_g[c] + gn_b[c];
    out[idx] = v > 0.f ? v : 0.f;
}

extern "C" void kernel_launch(void* const* d_in, const int* in_sizes, int n_in,
                              void* d_out, int out_size, void* d_ws, size_t ws_size,
                              hipStream_t stream) {
    const float* f    = (const float*)d_in[0];
    const float* offw = (const float*)d_in[1];
    const float* offb = (const float*)d_in[2];
    const float* bng  = (const float*)d_in[3];
    const float* bnb  = (const float*)d_in[4];
    const float* dcnw = (const float*)d_in[5];
    const float* dcnb = (const float*)d_in[6];
    const float* gng  = (const float*)d_in[7];
    const float* gnb  = (const float*)d_in[8];
    float* out = (float*)d_out;

    float* ws     = (float*)d_ws;
    float* ft     = ws;               // 8*VOX floats (featT)
    float* offs   = ws + 8 * VOX;     // 18*VOX floats (raw offset conv)
    float* stats  = offs + 18 * VOX;  // 36 bn stats + 8 gn stats
    float* gstats = stats + 36;
    // wT lives in d_out's first 3888 floats: dead until k_main overwrites out.
    float* wT = out;

    hipLaunchKernelGGL(k_setup, dim3(8209), dim3(256), 0, stream, f, ft, stats, offw, wT);
    hipLaunchKernelGGL(k_conv_off, dim3(2048), dim3(256), 0, stream,
                       f, wT, offb, offs, stats);
    hipLaunchKernelGGL(k_main, dim3(1024), dim3(256), 0, stream,
                       ft, offs, stats, bng, bnb, dcnw, dcnb, out, gstats);
    hipLaunchKernelGGL(k_gn, dim3((16 * VOX) / 256), dim3(256), 0, stream,
                       gstats, gng, gnb, out);
}

// Round 5
// 200.397 us; speedup vs baseline: 1.1206x; 1.1206x over previous
//
#include <hip/hip_runtime.h>
#include <math.h>

#define VOX 262144  // 64^3

__device__ __forceinline__ int clampi(int v, int lo, int hi) {
    return v < lo ? lo : (v > hi ? hi : v);
}

__device__ __forceinline__ float fast_tanh(float x) {
    float e = __expf(2.f * x);
    return 1.f - 2.f / (e + 1.f);
}

// ---- merged setup: feat transpose (blocks 0..8191), stats zero (8192),
//      weight transpose (8193..8208) ----
__global__ void k_setup(const float* __restrict__ f, float* __restrict__ ft,
                        float* __restrict__ stats, const float* __restrict__ w,
                        float* __restrict__ wT) {
    int bid = blockIdx.x;
    if (bid < 8192) {
        int idx = bid * 256 + threadIdx.x;  // (ci,z,y,x), coalesced reads
        int x = idx & 63, y = (idx >> 6) & 63, z = (idx >> 12) & 63, ci = idx >> 18;
        ft[(((z * 64 + y) * 64 + x) << 3) + ci] = f[idx];
    } else if (bid == 8192) {
        if (threadIdx.x < 64) stats[threadIdx.x] = 0.f;
    } else {
        int i = (bid - 8193) * 256 + threadIdx.x;  // over 18*8*27 = 3888
        if (i < 3888) {
            int c = i / 216, r = i % 216;
            int ci = r / 27, k = r % 27;
            wT[(k * 8 + ci) * 18 + c] = w[i];  // wT[k][ci][18]
        }
    }
}

// ---- offset conv (3x3x3, 8->18ch) + BN stats; CHANNEL-split across 2 groups ----
// 2048 blocks x 256: threads 0-127 -> out-ch 0..8, threads 128-255 -> ch 9..17,
// same 128 voxels (identical f loads -> L1 broadcast). x-neighbors via __shfl.
// XCD z-slab swizzle: block b -> slab b%8 (8 z-planes), keeps per-XCD L2 local.
__global__ __launch_bounds__(256, 8) void k_conv_off(
        const float* __restrict__ f, const float* __restrict__ wT,
        const float* __restrict__ b, float* __restrict__ offs,
        float* __restrict__ stats) {
    __shared__ float ls[36];
    if (threadIdx.x < 36) ls[threadIdx.x] = 0.f;

    int lv = threadIdx.x & 127;
    int g = __builtin_amdgcn_readfirstlane(threadIdx.x >> 7);  // 0/1, scalar
    int lane = threadIdx.x & 63;
    int slab = blockIdx.x & 7, inner = blockIdx.x >> 3;  // XCD swizzle
    int vox = slab * 32768 + inner * 128 + lv;
    int h = vox & 63, wy = (vox >> 6) & 63, d = vox >> 12;  // h == lane

    float mh0 = h > 0 ? 1.f : 0.f;
    float mh2 = h < 63 ? 1.f : 0.f;
    int sl0 = lane > 0 ? lane - 1 : 0;
    int sl2 = lane < 63 ? lane + 1 : 63;

    const float* wb = wT + 9 * g;  // scalar base -> s_load weights
    const float* bb = b + 9 * g;

    float acc[9];
#pragma unroll
    for (int c = 0; c < 9; c++) acc[c] = bb[c];

#pragma unroll
    for (int p = 0; p < 9; p++) {
        int kd = p / 3, kw = p % 3;
        int dd = d + kd - 1;
        int ww = wy + kw - 1;
        bool ok = ((unsigned)dd < 64u) & ((unsigned)ww < 64u);  // wave-uniform
        if (ok) {
            const float* fp = f + (dd * 64 + ww) * 64 + h;
#pragma unroll
            for (int ci = 0; ci < 8; ci++) {
                float v1 = fp[ci * VOX];
                float v0 = __shfl(v1, sl0) * mh0;
                float v2 = __shfl(v1, sl2) * mh2;
                const float* wp = wb + ((p * 3) * 8 + ci) * 18;
#pragma unroll
                for (int c = 0; c < 9; c++) {
                    float a = acc[c];
                    a = fmaf(v0, wp[c], a);
                    a = fmaf(v1, wp[8 * 18 + c], a);
                    a = fmaf(v2, wp[16 * 18 + c], a);
                    acc[c] = a;
                }
            }
        }
    }

#pragma unroll
    for (int c = 0; c < 9; c++) offs[(9 * g + c) * VOX + vox] = acc[c];

    __syncthreads();  // ls zeroed before atomics
#pragma unroll
    for (int c = 0; c < 9; c++) {
        float s = acc[c], q = acc[c] * acc[c];
#pragma unroll
        for (int o = 32; o > 0; o >>= 1) {
            s += __shfl_xor(s, o);
            q += __shfl_xor(q, o);
        }
        if (lane == 0) {
            atomicAdd(&ls[9 * g + c], s);
            atomicAdd(&ls[18 + 9 * g + c], q);
        }
    }
    __syncthreads();
    if (threadIdx.x < 36) atomicAdd(&stats[threadIdx.x], ls[threadIdx.x]);
}

// ---- main: BN+tanh+cumsum + bilinear(z,y) gather + (1,1,9) conv + GN stats.
//      R2 structure (per-tap branch) + XCD z-slab swizzle for L2 locality. ----
__global__ __launch_bounds__(256) void k_main(
        const float* __restrict__ ft, const float* __restrict__ offs,
        const float* __restrict__ stats, const float* __restrict__ bn_g,
        const float* __restrict__ bn_b, const float* __restrict__ dw,
        const float* __restrict__ db, float* __restrict__ out,
        float* __restrict__ gstats) {
    __shared__ float ls[8];
    if (threadIdx.x < 8) ls[threadIdx.x] = 0.f;

    int slab = blockIdx.x & 7, inner = blockIdx.x >> 3;  // XCD swizzle
    int vox = slab * 32768 + inner * 256 + threadIdx.x;  // XCD x owns z in [8x,8x+8)
    int h = vox & 63, wy = (vox >> 6) & 63, d = vox >> 12;
    int lane = threadIdx.x & 63;
    const float inv = 1.f / (float)VOX;

    float zo[9], yo[9];
#pragma unroll
    for (int c = 0; c < 18; c++) {
        float m = stats[c] * inv;
        float var = stats[18 + c] * inv - m * m;
        float rs = rsqrtf(var + 1e-5f);
        float t = fast_tanh(bn_g[c] * ((offs[c * VOX + vox] - m) * rs) + bn_b[c]);
        if (c < 9) zo[c] = t; else yo[c - 9] = t;
    }

    // cumsum outward from center (K=9, CENTER=4)
    float za[9], ya[9];
    za[4] = zo[4]; ya[4] = yo[4];
#pragma unroll
    for (int k = 5; k < 9; k++) { za[k] = za[k - 1] + zo[k]; ya[k] = ya[k - 1] + yo[k]; }
#pragma unroll
    for (int k = 3; k >= 0; k--) { za[k] = za[k + 1] + zo[k]; ya[k] = ya[k + 1] + yo[k]; }

    float acc[16];
#pragma unroll
    for (int co = 0; co < 16; co++) acc[co] = db[co];

#pragma unroll
    for (int k = 0; k < 9; k++) {
        int xi = h + k - 4;
        // x is exactly integer: weight 1 for xi in [0,62], exactly 0 otherwise
        if (xi >= 0 && xi <= 62) {
            float z = (float)d + za[k];
            float y = (float)wy + ya[k];
            int iz = (int)floorf(z), iy = (int)floorf(y);
            int z0 = clampi(iz, 0, 63), z1 = clampi(iz + 1, 0, 63);
            int y0 = clampi(iy, 0, 63), y1 = clampi(iy + 1, 0, 63);
            float wz0 = (float)z1 - z, wz1 = z - (float)z0;
            float wy0 = (float)y1 - y, wy1 = y - (float)y0;
            float w00 = wz0 * wy0, w01 = wz0 * wy1, w10 = wz1 * wy0, w11 = wz1 * wy1;

            const float4* p00 = (const float4*)(ft + (((z0 * 64 + y0) * 64 + xi) << 3));
            const float4* p01 = (const float4*)(ft + (((z0 * 64 + y1) * 64 + xi) << 3));
            const float4* p10 = (const float4*)(ft + (((z1 * 64 + y0) * 64 + xi) << 3));
            const float4* p11 = (const float4*)(ft + (((z1 * 64 + y1) * 64 + xi) << 3));
            float4 a00 = p00[0], b00 = p00[1];
            float4 a01 = p01[0], b01 = p01[1];
            float4 a10 = p10[0], b10 = p10[1];
            float4 a11 = p11[0], b11 = p11[1];

            float v[8];
            v[0] = w00 * a00.x + w01 * a01.x + w10 * a10.x + w11 * a11.x;
            v[1] = w00 * a00.y + w01 * a01.y + w10 * a10.y + w11 * a11.y;
            v[2] = w00 * a00.z + w01 * a01.z + w10 * a10.z + w11 * a11.z;
            v[3] = w00 * a00.w + w01 * a01.w + w10 * a10.w + w11 * a11.w;
            v[4] = w00 * b00.x + w01 * b01.x + w10 * b10.x + w11 * b11.x;
            v[5] = w00 * b00.y + w01 * b01.y + w10 * b10.y + w11 * b11.y;
            v[6] = w00 * b00.z + w01 * b01.z + w10 * b10.z + w11 * b11.z;
            v[7] = w00 * b00.w + w01 * b01.w + w10 * b10.w + w11 * b11.w;

#pragma unroll
            for (int ci = 0; ci < 8; ci++) {
#pragma unroll
                for (int co = 0; co < 16; co++)
                    acc[co] = fmaf(v[ci], dw[(co * 8 + ci) * 9 + k], acc[co]);
            }
        }
    }

#pragma unroll
    for (int co = 0; co < 16; co++) out[co * VOX + vox] = acc[co];

    __syncthreads();  // ls zeroed before atomics
#pragma unroll
    for (int g = 0; g < 4; g++) {
        float s = acc[4 * g] + acc[4 * g + 1] + acc[4 * g + 2] + acc[4 * g + 3];
        float q = acc[4 * g] * acc[4 * g] + acc[4 * g + 1] * acc[4 * g + 1]
                + acc[4 * g + 2] * acc[4 * g + 2] + acc[4 * g + 3] * acc[4 * g + 3];
#pragma unroll
        for (int o = 32; o > 0; o >>= 1) {
            s += __shfl_xor(s, o);
            q += __shfl_xor(q, o);
        }
        if (lane == 0) {
            atomicAdd(&ls[g], s);
            atomicAdd(&ls[4 + g], q);
        }
    }
    __syncthreads();
    if (threadIdx.x < 8) atomicAdd(&gstats[threadIdx.x], ls[threadIdx.x]);
}

// ---- apply GroupNorm + ReLU in place on d_out ----
__global__ void k_gn(const float* __restrict__ gstats, const float* __restrict__ gn_g,
                     const float* __restrict__ gn_b, float* __restrict__ out) {
    int idx = blockIdx.x * 256 + threadIdx.x;  // 16*VOX elements
    int c = idx >> 18;
    int g = c >> 2;
    const float invn = 1.f / (4.f * (float)VOX);
    float m = gstats[g] * invn;
    float var = gstats[4 + g] * invn - m * m;
    float rs = rsqrtf(var + 1e-5f);
    float v = (out[idx] - m) * rs * gn_g[c] + gn_b[c];
    out[idx] = v > 0.f ? v : 0.f;
}

extern "C" void kernel_launch(void* const* d_in, const int* in_sizes, int n_in,
                              void* d_out, int out_size, void* d_ws, size_t ws_size,
                              hipStream_t stream) {
    const float* f    = (const float*)d_in[0];
    const float* offw = (const float*)d_in[1];
    const float* offb = (const float*)d_in[2];
    const float* bng  = (const float*)d_in[3];
    const float* bnb  = (const float*)d_in[4];
    const float* dcnw = (const float*)d_in[5];
    const float* dcnb = (const float*)d_in[6];
    const float* gng  = (const float*)d_in[7];
    const float* gnb  = (const float*)d_in[8];
    float* out = (float*)d_out;

    float* ws     = (float*)d_ws;
    float* ft     = ws;               // 8*VOX floats (featT)
    float* offs   = ws + 8 * VOX;     // 18*VOX floats (raw offset conv)
    float* stats  = offs + 18 * VOX;  // 36 bn stats + 8 gn stats
    float* gstats = stats + 36;
    // wT lives in d_out's first 3888 floats: dead until k_main overwrites out.
    float* wT = out;

    hipLaunchKernelGGL(k_setup, dim3(8209), dim3(256), 0, stream, f, ft, stats, offw, wT);
    hipLaunchKernelGGL(k_conv_off, dim3(2048), dim3(256), 0, stream,
                       f, wT, offb, offs, stats);
    hipLaunchKernelGGL(k_main, dim3(1024), dim3(256), 0, stream,
                       ft, offs, stats, bng, bnb, dcnw, dcnb, out, gstats);
    hipLaunchKernelGGL(k_gn, dim3((16 * VOX) / 256), dim3(256), 0, stream,
                       gstats, gng, gnb, out);
}